// Round 9
// baseline (441.633 us; speedup 1.0000x reference)
//
#include <hip/hip_runtime.h>

typedef __attribute__((ext_vector_type(8))) short bfx8;
typedef __attribute__((ext_vector_type(4))) short bfx4;
typedef __attribute__((ext_vector_type(4))) float fx4;
typedef __attribute__((ext_vector_type(4))) int   ix4;

// ---- LDS layout (bytes) ----
#define OA   0                  // A' 64x64 bf16 pitch 64        (8K)
#define OB0  8192               // Xt -> Hphi_t -> Mp[0:128) f32 -> He2   (32K)
#define OB1  40960              // Mhi -> Me -> {X2t, ASt, A2, v, w, u, t1} (32K)
#define OB2  73728              // Mlo -> Hplo_t -> Mp[128:256) f32 -> Zt (32K)
#define OB3  106496             // He_t -> M2                              (32K)
#define OSP  139264             // Sp f32 64x32 pitch 32                   (8K)
#define OST  147456             // S^T 32x64 bf16 pitch 64                 (4K)
#define OX2  OB1                // X2^T 256x32 bf16 pitch 32              (16K)
#define OAS  (OB1+16384)        // AS^T 32x64 bf16 pitch 64                (4K)
#define OA2  (OB1+20480)        // A2' 32x32 bf16 pitch 32                 (2K)
#define OV   (OB1+22528)        // v 32 f32
#define OW   (OB1+22656)        // w 256 f32
#define OU   (OB1+23680)        // u 256 f32
#define OT1  (OB1+24704)        // t1 512 f32
#define LDS_TOTAL 151552

__device__ __forceinline__ short f2bf(float f){
    union{float f;unsigned u;}v; v.f=f;
    unsigned r = v.u + 0x7FFFu + ((v.u>>16)&1u);
    return (short)(r>>16);
}
__device__ __forceinline__ float bf2f(short s){
    union{unsigned u;float f;}v; v.u = ((unsigned)(unsigned short)s)<<16; return v.f;
}

// swizzled byte offsets: XOR row-low-bits into byte bits 4..6 (keeps 16B units)
__device__ __forceinline__ int so16(int r,int c,int pitch){ return ((r*pitch+c)*2) ^ ((r&7)<<4); }
__device__ __forceinline__ int so32(int r,int c,int pitch){ return ((r*pitch+c)*4) ^ ((r&7)<<4); }
__device__ __forceinline__ int mpoff(int r,int c){           // Mp f32, cols split B0/B2
    int base = (c&128)? OB2 : OB0;
    return base + so32(r, c&127, 128);
}

// fragment load: lane holds elem (r0+lane%16, k0+8*(lane/16)+j)  [A-op rows / B-op cols]
__device__ __forceinline__ bfx8 ldfrag(const char* sm,int boff,int r0,int k0,int pitch,int lane){
    int r = r0 + (lane&15);
    int c = k0 + ((lane>>4)<<3);
    return *(const bfx8*)(sm + boff + so16(r,c,pitch));
}

// ---- GEMM helpers, ks-OUTER ordering ----
// Round-7 post-mortem: fully-unrolled (tile-outer, ks-inner) bodies exposed
// 64 independent global B-frag loads per call; scheduler hoisted them ->
// ~27MB/dispatch scratch spill-writeback (WRITE_SIZE), kernel HBM-bound on
// spills. ks-outer with runtime loop bounds live B-frags to TPW per step.
// C = A_lds(MxK) * B_lds^T-stored(KxN)
template<int NTL,int KS,int TPW,bool ADD>
__device__ __forceinline__ void gemm_ll_t(const char* sm,int aoff,int ap,int boff,int bp,
                                          int lane,int w,fx4* acc){
    if(!ADD){
#pragma unroll
        for(int i=0;i<TPW;i++) acc[i]=fx4{0.f,0.f,0.f,0.f};
    }
#pragma unroll
    for(int ks=0;ks<KS;ks++){
#pragma unroll
        for(int i=0;i<TPW;i++){
            int t=w*TPW+i, mt=t>>NTL, nt=t&((1<<NTL)-1);
            bfx8 a = ldfrag(sm,aoff,mt<<4,ks<<5,ap,lane);
            bfx8 b = ldfrag(sm,boff,nt<<4,ks<<5,bp,lane);
            acc[i] = __builtin_amdgcn_mfma_f32_16x16x32_bf16(a,b,acc[i],0,0,0);
        }
    }
}
// C = A_lds(MxK) * B_packedglobal(KxN); runtime ks loop caps register demand
template<int NTL,int KS,int TPW,bool ADD>
__device__ __forceinline__ void gemm_lg_t(const char* sm,int aoff,int ap,const bfx8* pk,
                                          int lane,int w,fx4* acc){
    if(!ADD){
#pragma unroll
        for(int i=0;i<TPW;i++) acc[i]=fx4{0.f,0.f,0.f,0.f};
    }
#pragma unroll 1
    for(int ks=0;ks<KS;ks++){
#pragma unroll
        for(int i=0;i<TPW;i++){
            int t=w*TPW+i, mt=t>>NTL, nt=t&((1<<NTL)-1);
            bfx8 a = ldfrag(sm,aoff,mt<<4,ks<<5,ap,lane);
            bfx8 b = pk[(nt*KS+ks)*64 + lane];
            acc[i] = __builtin_amdgcn_mfma_f32_16x16x32_bf16(a,b,acc[i],0,0,0);
        }
    }
}

// C-frag layout: col = n0+(lane&15), rows = m0+4*(lane>>4)+q
template<int NTL,int TPW>
__device__ __forceinline__ void st_norm(char* sm,int boff,int pitch,int lane,int w,
                                        const fx4* acc,bool relu){
#pragma unroll
    for(int i=0;i<TPW;i++){
        int t=w*TPW+i, mt=t>>NTL, nt=t&((1<<NTL)-1);
        int col=(nt<<4)+(lane&15), rb=(mt<<4)+((lane>>4)<<2);
#pragma unroll
        for(int q=0;q<4;q++){
            float v=acc[i][q]; if(relu) v=fmaxf(v,0.f);
            *(short*)(sm+boff+so16(rb+q,col,pitch)) = f2bf(v);
        }
    }
}
template<int NTL,int TPW>
__device__ __forceinline__ void st_norm_hilo(char* sm,int bhi,int blo,int pitch,int lane,int w,
                                             const fx4* acc,bool relu){
#pragma unroll
    for(int i=0;i<TPW;i++){
        int t=w*TPW+i, mt=t>>NTL, nt=t&((1<<NTL)-1);
        int col=(nt<<4)+(lane&15), rb=(mt<<4)+((lane>>4)<<2);
#pragma unroll
        for(int q=0;q<4;q++){
            float v=acc[i][q]; if(relu) v=fmaxf(v,0.f);
            short hi=f2bf(v);
            *(short*)(sm+bhi+so16(rb+q,col,pitch)) = hi;
            *(short*)(sm+blo+so16(rb+q,col,pitch)) = f2bf(v - bf2f(hi));
        }
    }
}
template<int NTL,int TPW>
__device__ __forceinline__ void st_tr(char* sm,int boff,int pitch,int lane,int w,
                                      const fx4* acc,bool relu){
#pragma unroll
    for(int i=0;i<TPW;i++){
        int t=w*TPW+i, mt=t>>NTL, nt=t&((1<<NTL)-1);
        int rn=(nt<<4)+(lane&15), cb=(mt<<4)+((lane>>4)<<2);
        bfx4 p;
#pragma unroll
        for(int q=0;q<4;q++){ float v=acc[i][q]; if(relu) v=fmaxf(v,0.f); p[q]=f2bf(v); }
        *(bfx4*)(sm+boff+so16(rn,cb,pitch)) = p;
    }
}
template<int NTL,int TPW>
__device__ __forceinline__ void st_tr_hilo(char* sm,int bhi,int blo,int pitch,int lane,int w,
                                           const fx4* acc,bool relu){
#pragma unroll
    for(int i=0;i<TPW;i++){
        int t=w*TPW+i, mt=t>>NTL, nt=t&((1<<NTL)-1);
        int rn=(nt<<4)+(lane&15), cb=(mt<<4)+((lane>>4)<<2);
        bfx4 ph, pl;
#pragma unroll
        for(int q=0;q<4;q++){
            float v=acc[i][q]; if(relu) v=fmaxf(v,0.f);
            short hi=f2bf(v); ph[q]=hi; pl[q]=f2bf(v - bf2f(hi));
        }
        *(bfx4*)(sm+bhi+so16(rn,cb,pitch)) = ph;
        *(bfx4*)(sm+blo+so16(rn,cb,pitch)) = pl;
    }
}
template<int TPW>
__device__ __forceinline__ void st_mp(char* sm,int lane,int w,const fx4* acc){
#pragma unroll
    for(int i=0;i<TPW;i++){
        int t=w*TPW+i, mt=t>>4, nt=t&15;
        int col=(nt<<4)+(lane&15), rb=(mt<<4)+((lane>>4)<<2);
#pragma unroll
        for(int q=0;q<4;q++) *(float*)(sm+mpoff(rb+q,col)) = acc[i][q];
    }
}

// ---- weight prepack: seg 0:Wp1hi 1:Wp1lo 2:We1hi 3:We2hi 4:We21hi (all 256x256) ----
// B-frag tile (kt,nt): out[((nt*8+kt)*64+lane)*8 + j] = W[kt*32+8*(lane/16)+j][nt*16+lane%16]
__global__ __launch_bounds__(256) void prepack_k(const float* __restrict__ Wp1,const float* __restrict__ We1,
                                                 const float* __restrict__ We2,const float* __restrict__ We21,
                                                 short* __restrict__ outp){
    int g = blockIdx.x; int seg = g>>5;
    int t = ((g&31)<<8) + threadIdx.x;          // [0,8192)
    int lane = t&63, tile = t>>6, kt = tile&7, nt = tile>>3;
    const float* W = (seg<2)? Wp1 : (seg==2)? We1 : (seg==3)? We2 : We21;
    int kb  = (kt<<5) + ((lane>>4)<<3);
    int col = (nt<<4) + (lane&15);
    bfx8 o;
#pragma unroll
    for(int j=0;j<8;j++){
        float v = W[(kb+j)*256 + col];
        short hi = f2bf(v);
        o[j] = (seg==1)? f2bf(v - bf2f(hi)) : hi;
    }
    ((bfx8*)outp)[seg*8192 + t] = o;
}

// ---- per-graph megakernel: 64 blocks x 512 threads (8 waves = 2/SIMD) ----
__global__ __launch_bounds__(512, 2) void mega_k(const float* __restrict__ x, const int* __restrict__ ei,
        const float* __restrict__ Wp2,  const float* __restrict__ We22,
        const float* __restrict__ l1W,  const float* __restrict__ l1b,
        const float* __restrict__ l2W,  const float* __restrict__ l2b,
        const short* __restrict__ pks,  float* __restrict__ out){
    extern __shared__ char sm[];
    const int tid = threadIdx.x, lane = tid&63, w = tid>>6, b = blockIdx.x;
    const bfx8* pkWp1hi = (const bfx8*)pks;
    const bfx8* pkWp1lo = pkWp1hi + 8192;
    const bfx8* pkWe1   = pkWp1hi + 16384;
    const bfx8* pkWe2   = pkWp1hi + 24576;
    const bfx8* pkWe21  = pkWp1hi + 32768;
    fx4 acc[8];

    // S0: zero A', stage X^T (bf16, swizzled); float4 global reads
    *(ix4*)(sm + OA + tid*16) = ix4{0,0,0,0};
#pragma unroll
    for(int ch=0; ch<8; ch++){
        int i2 = tid + (ch<<9);                   // [0,4096) float4 groups
        int r = i2>>6, c0 = (i2&63)<<2;
        fx4 v = *(const fx4*)(x + (size_t)(((b<<6)+r)<<8) + c0);
#pragma unroll
        for(int j=0;j<4;j++)
            *(short*)(sm + OB0 + so16(c0+j, r, 64)) = f2bf(v[j]);
    }
    __syncthreads();
    // S1: edges of graph b are e = b + 64*t  (structural: base=(e%64)*64)
#pragma unroll
    for(int q=0;q<2;q++){
        int e = b + (((tid<<1)+q)<<6);
        int s = ei[e]&63, d = ei[e+65536]&63;
        *(short*)(sm + OA + so16(s, d, 64)) = (short)0x3F80;   // 1.0bf16
    }
    __syncthreads();
    if(tid<64){                                                // A' = A + I (0/1 -> 1/2 exact)
        int off = OA + so16(tid, tid, 64);
        *(short*)(sm+off) = f2bf(bf2f(*(short*)(sm+off)) + 1.0f);
    }
    __syncthreads();

    // S2: M = A'X  -> Mhi(B1) + Mlo(B2), row-major pitch 256
    gemm_ll_t<4,2,8,false>(sm, OA,64, OB0,64, lane,w, acc);
    st_norm_hilo<4,8>(sm, OB1, OB2, 256, lane,w, acc, false);
    __syncthreads();

    // S3: He = relu(Mhi@We1) -> He^T (B3, pitch 64)
    gemm_lg_t<4,8,8,false>(sm, OB1,256, pkWe1, lane,w, acc);
    st_tr<4,8>(sm, OB3, 64, lane,w, acc, true);
    __builtin_amdgcn_sched_barrier(0);
    // S4: Hp = relu(M@Wp1) split-precision (3 passes)
    gemm_lg_t<4,8,8,false>(sm, OB1,256, pkWp1hi, lane,w, acc);
    __builtin_amdgcn_sched_barrier(0);
    gemm_lg_t<4,8,8,true >(sm, OB1,256, pkWp1lo, lane,w, acc);
    __builtin_amdgcn_sched_barrier(0);
    gemm_lg_t<4,8,8,true >(sm, OB2,256, pkWp1hi, lane,w, acc);
    __syncthreads();
    st_tr_hilo<4,8>(sm, OB0, OB2, 64, lane,w, acc, true);      // Hphi^T(B0), Hplo^T(B2)
    __syncthreads();

    // S5: Mp = A'(Hphi+Hplo), f32 in LDS (B0|B2)
    gemm_ll_t<4,2,8,false>(sm, OA,64, OB0,64, lane,w, acc);
    gemm_ll_t<4,2,8,true >(sm, OA,64, OB2,64, lane,w, acc);
    __syncthreads();
    st_mp<8>(sm, lane,w, acc);
    __syncthreads();

    // S6: Sp = Mp @ Wp2 (f32 VALU), 64x32
    {
        int r = tid>>3, sg = tid&7;
        float a0=0.f,a1=0.f,a2=0.f,a3=0.f;
#pragma unroll 1
        for(int c=0;c<256;c++){
            float m = *(const float*)(sm + mpoff(r,c));
            fx4 wv = *(const fx4*)(Wp2 + (c<<5) + (sg<<2));
            a0 += m*wv[0]; a1 += m*wv[1]; a2 += m*wv[2]; a3 += m*wv[3];
        }
        *(float*)(sm+OSP+so32(r,(sg<<2)+0,32))=a0;
        *(float*)(sm+OSP+so32(r,(sg<<2)+1,32))=a1;
        *(float*)(sm+OSP+so32(r,(sg<<2)+2,32))=a2;
        *(float*)(sm+OSP+so32(r,(sg<<2)+3,32))=a3;
    }
    __syncthreads();
    // S7: row-softmax (f32) -> S^T bf16 (OST)
    {
        int r = tid>>3, j = tid&7;
        float v0=*(const float*)(sm+OSP+so32(r,(j<<2)+0,32));
        float v1=*(const float*)(sm+OSP+so32(r,(j<<2)+1,32));
        float v2=*(const float*)(sm+OSP+so32(r,(j<<2)+2,32));
        float v3=*(const float*)(sm+OSP+so32(r,(j<<2)+3,32));
        float mx = fmaxf(fmaxf(v0,v1),fmaxf(v2,v3));
#pragma unroll
        for(int o=1;o<8;o<<=1) mx = fmaxf(mx, __shfl_xor(mx,o,64));
        float e0=__expf(v0-mx), e1=__expf(v1-mx), e2=__expf(v2-mx), e3=__expf(v3-mx);
        float s = e0+e1+e2+e3;
#pragma unroll
        for(int o=1;o<8;o<<=1) s += __shfl_xor(s,o,64);
        float inv = 1.f/s;
        *(short*)(sm+OST+so16((j<<2)+0,r,64)) = f2bf(e0*inv);
        *(short*)(sm+OST+so16((j<<2)+1,r,64)) = f2bf(e1*inv);
        *(short*)(sm+OST+so16((j<<2)+2,r,64)) = f2bf(e2*inv);
        *(short*)(sm+OST+so16((j<<2)+3,r,64)) = f2bf(e3*inv);
    }
    __syncthreads();

    // S8: Me = A'He -> row-major (B1)
    gemm_ll_t<4,2,8,false>(sm, OA,64, OB3,64, lane,w, acc);
    st_norm<4,8>(sm, OB1, 256, lane,w, acc, false);
    __syncthreads();
    // S9: Z = Me@We2 -> Z^T (B2)
    gemm_lg_t<4,8,8,false>(sm, OB1,256, pkWe2, lane,w, acc);
    st_tr<4,8>(sm, OB2, 64, lane,w, acc, false);
    __syncthreads();
    // S10: X2 = S^T Z (32x256) -> X2^T (OX2, pitch 32)
    gemm_ll_t<4,2,4,false>(sm, OST,64, OB2,64, lane,w, acc);
    st_tr<4,4>(sm, OX2, 32, lane,w, acc, false);
    __syncthreads();
    // S11: AS = A@S = A'S - S -> AS^T (OAS)
    {
        gemm_ll_t<1,2,1,false>(sm, OA,64, OST,64, lane,w, acc);
        int mt = w>>1, nt = w&1;
        int tcol = (nt<<4)+(lane&15), cb = (mt<<4)+((lane>>4)<<2);
        bfx4 p;
#pragma unroll
        for(int q=0;q<4;q++){
            float v = acc[0][q] - bf2f(*(const short*)(sm+OST+so16(tcol,cb+q,64)));
            p[q]=f2bf(v);
        }
        *(bfx4*)(sm+OAS+so16(tcol,cb,64)) = p;
    }
    __syncthreads();
    // S12: A2' = S^T AS + I -> OA2 (32x32)
    if(w<4){
        gemm_ll_t<1,2,1,false>(sm, OST,64, OAS,64, lane,w, acc);
        int mt=w>>1, nt=w&1;
        int col=(nt<<4)+(lane&15), rb=(mt<<4)+((lane>>4)<<2);
#pragma unroll
        for(int q=0;q<4;q++){
            float v = acc[0][q] + ((rb+q)==col ? 1.f : 0.f);
            *(short*)(sm+OA2+so16(rb+q,col,32)) = f2bf(v);
        }
    }
    __syncthreads();
    // S13: v = colsum(A2')
    if(tid<32){
        float s=0.f;
#pragma unroll
        for(int r=0;r<32;r++) s += bf2f(*(const short*)(sm+OA2+so16(r,tid,32)));
        *(float*)(sm+OV+(tid<<2)) = s;
    }
    __syncthreads();
    // S14: M2 = A2' X2 -> row-major (B3)
    gemm_ll_t<4,1,4,false>(sm, OA2,32, OX2,32, lane,w, acc);
    st_norm<4,4>(sm, OB3, 256, lane,w, acc, false);
    __syncthreads();
    // S15: He2 = relu(M2@We21) -> row-major (B0)
    gemm_lg_t<4,8,4,false>(sm, OB3,256, pkWe21, lane,w, acc);
    st_norm<4,4>(sm, OB0, 256, lane,w, acc, true);
    __syncthreads();
    // S16: w = v^T He2
    if(tid<256){
        float a=0.f;
#pragma unroll
        for(int n=0;n<32;n++)
            a += *(const float*)(sm+OV+(n<<2)) * bf2f(*(const short*)(sm+OB0+so16(n,tid,256)));
        *(float*)(sm+OW+(tid<<2)) = a;
    }
    __syncthreads();
    // S17: u = 0.125 * w @ We22 (f32 global weights)
    if(tid<256){
        float a=0.f;
#pragma unroll 1
        for(int k=0;k<256;k++) a += *(const float*)(sm+OW+(k<<2)) * We22[(k<<8)+tid];
        *(float*)(sm+OU+(tid<<2)) = 0.125f*a;
    }
    __syncthreads();
    // S18: t1 = relu(u@lin1 + b1)
    {
        float a = l1b[tid];
#pragma unroll 1
        for(int k=0;k<256;k++) a += *(const float*)(sm+OU+(k<<2)) * l1W[(k<<9)+tid];
        *(float*)(sm+OT1+(tid<<2)) = fmaxf(a,0.f);
    }
    __syncthreads();
    // S19: out = t1@lin2 + b2
    if(tid<256){
        float a = l2b[tid];
#pragma unroll 1
        for(int k=0;k<512;k++) a += *(const float*)(sm+OT1+(k<<2)) * l2W[(k<<8)+tid];
        out[(b<<8)+tid] = a;
    }
}

extern "C" void kernel_launch(void* const* d_in, const int* in_sizes, int n_in,
                              void* d_out, int out_size, void* d_ws, size_t ws_size,
                              hipStream_t stream) {
    const float* x    = (const float*)d_in[0];
    const int*   ei   = (const int*)d_in[1];
    const float* p0W1 = (const float*)d_in[3];
    const float* p0W2 = (const float*)d_in[4];
    const float* e0W1 = (const float*)d_in[5];
    const float* e0W2 = (const float*)d_in[6];
    // d_in[7], d_in[8]: pool1 weights are mathematically dead (softmax rows sum to 1 under mean-pool)
    const float* e1W1 = (const float*)d_in[9];
    const float* e1W2 = (const float*)d_in[10];
    const float* l1W  = (const float*)d_in[11];
    const float* l1b  = (const float*)d_in[12];
    const float* l2W  = (const float*)d_in[13];
    const float* l2b  = (const float*)d_in[14];
    float* out = (float*)d_out;
    short* pks = (short*)d_ws;          // 655360 B of packed bf16 weights

    hipFuncSetAttribute((const void*)mega_k, hipFuncAttributeMaxDynamicSharedMemorySize, LDS_TOTAL);
    prepack_k<<<160, 256, 0, stream>>>(p0W1, e0W1, e0W2, e1W1, pks);
    mega_k<<<64, 512, LDS_TOTAL, stream>>>(x, ei, p0W2, e1W2, l1W, l1b, l2W, l2b, pks, out);
}

// Round 14
// 195.992 us; speedup vs baseline: 2.2533x; 2.2533x over previous
//
#include <hip/hip_runtime.h>

typedef __attribute__((ext_vector_type(8))) short bfx8;
typedef __attribute__((ext_vector_type(4))) short bfx4;
typedef __attribute__((ext_vector_type(4))) float fx4;
typedef __attribute__((ext_vector_type(4))) int   ix4;

// ---- LDS layout (bytes) ----
#define OA   0                  // A' 64x64 bf16 pitch 64        (8K)
#define OB0  8192               // Xt -> Hphi_t -> Mp[0:128) f32 -> He2   (32K)
#define OB1  40960              // Mhi -> Me -> {X2t, ASt, A2, v, w, u, t1} (32K)
#define OB2  73728              // Mlo -> Hplo_t -> Mp[128:256) f32 -> Zt (32K)
#define OB3  106496             // He_t -> M2                              (32K)
#define OSP  139264             // Sp f32 64x32 pitch 32                   (8K)
#define OST  147456             // S^T 32x64 bf16 pitch 64                 (4K)
#define OX2  OB1                // X2^T 256x32 bf16 pitch 32              (16K)
#define OAS  (OB1+16384)        // AS^T 32x64 bf16 pitch 64                (4K)
#define OA2  (OB1+20480)        // A2' 32x32 bf16 pitch 32                 (2K)
#define OV   (OB1+22528)        // v 32 f32
#define OW   (OB1+22656)        // w 256 f32
#define OU   (OB1+23680)        // u 256 f32
#define OT1  (OB1+24704)        // t1 512 f32
#define LDS_TOTAL 151552

__device__ __forceinline__ short f2bf(float f){
    union{float f;unsigned u;}v; v.f=f;
    unsigned r = v.u + 0x7FFFu + ((v.u>>16)&1u);
    return (short)(r>>16);
}
__device__ __forceinline__ float bf2f(short s){
    union{unsigned u;float f;}v; v.u = ((unsigned)(unsigned short)s)<<16; return v.f;
}

// swizzled byte offsets: XOR row-low-bits into byte bits 4..6 (keeps 16B units)
__device__ __forceinline__ int so16(int r,int c,int pitch){ return ((r*pitch+c)*2) ^ ((r&7)<<4); }
__device__ __forceinline__ int so32(int r,int c,int pitch){ return ((r*pitch+c)*4) ^ ((r&7)<<4); }
__device__ __forceinline__ int mpoff(int r,int c){           // Mp f32, cols split B0/B2
    int base = (c&128)? OB2 : OB0;
    return base + so32(r, c&127, 128);
}

// fragment load: lane holds elem (r0+lane%16, k0+8*(lane/16)+j)  [A-op rows / B-op cols]
__device__ __forceinline__ bfx8 ldfrag(const char* sm,int boff,int r0,int k0,int pitch,int lane){
    int r = r0 + (lane&15);
    int c = k0 + ((lane>>4)<<3);
    return *(const bfx8*)(sm + boff + so16(r,c,pitch));
}

// ---- GEMM helpers, ks-OUTER ordering with BOUNDED ILP ----
// Round-7: full unroll -> 64 hoisted B-frags -> 27MB spill writeback.
// Round-9: unroll 1 -> serialized load latency (~300cyc/iter) -> 380us.
// Fix: unroll 2 -> 16 B-frags in flight (64 VGPR), latency pipelined, no spill.
// C = A_lds(MxK) * B_lds^T-stored(KxN)
template<int NTL,int KS,int TPW,bool ADD>
__device__ __forceinline__ void gemm_ll_t(const char* sm,int aoff,int ap,int boff,int bp,
                                          int lane,int w,fx4* acc){
    if(!ADD){
#pragma unroll
        for(int i=0;i<TPW;i++) acc[i]=fx4{0.f,0.f,0.f,0.f};
    }
#pragma unroll
    for(int ks=0;ks<KS;ks++){
#pragma unroll
        for(int i=0;i<TPW;i++){
            int t=w*TPW+i, mt=t>>NTL, nt=t&((1<<NTL)-1);
            bfx8 a = ldfrag(sm,aoff,mt<<4,ks<<5,ap,lane);
            bfx8 b = ldfrag(sm,boff,nt<<4,ks<<5,bp,lane);
            acc[i] = __builtin_amdgcn_mfma_f32_16x16x32_bf16(a,b,acc[i],0,0,0);
        }
    }
}
// C = A_lds(MxK) * B_packedglobal(KxN); unroll 2 = 2 ks-steps of loads in flight
template<int NTL,int KS,int TPW,bool ADD>
__device__ __forceinline__ void gemm_lg_t(const char* sm,int aoff,int ap,const bfx8* pk,
                                          int lane,int w,fx4* acc){
    if(!ADD){
#pragma unroll
        for(int i=0;i<TPW;i++) acc[i]=fx4{0.f,0.f,0.f,0.f};
    }
#pragma unroll 2
    for(int ks=0;ks<KS;ks++){
#pragma unroll
        for(int i=0;i<TPW;i++){
            int t=w*TPW+i, mt=t>>NTL, nt=t&((1<<NTL)-1);
            bfx8 a = ldfrag(sm,aoff,mt<<4,ks<<5,ap,lane);
            bfx8 b = pk[(nt*KS+ks)*64 + lane];
            acc[i] = __builtin_amdgcn_mfma_f32_16x16x32_bf16(a,b,acc[i],0,0,0);
        }
    }
}

// C-frag layout: col = n0+(lane&15), rows = m0+4*(lane>>4)+q
template<int NTL,int TPW>
__device__ __forceinline__ void st_norm(char* sm,int boff,int pitch,int lane,int w,
                                        const fx4* acc,bool relu){
#pragma unroll
    for(int i=0;i<TPW;i++){
        int t=w*TPW+i, mt=t>>NTL, nt=t&((1<<NTL)-1);
        int col=(nt<<4)+(lane&15), rb=(mt<<4)+((lane>>4)<<2);
#pragma unroll
        for(int q=0;q<4;q++){
            float v=acc[i][q]; if(relu) v=fmaxf(v,0.f);
            *(short*)(sm+boff+so16(rb+q,col,pitch)) = f2bf(v);
        }
    }
}
template<int NTL,int TPW>
__device__ __forceinline__ void st_norm_hilo(char* sm,int bhi,int blo,int pitch,int lane,int w,
                                             const fx4* acc,bool relu){
#pragma unroll
    for(int i=0;i<TPW;i++){
        int t=w*TPW+i, mt=t>>NTL, nt=t&((1<<NTL)-1);
        int col=(nt<<4)+(lane&15), rb=(mt<<4)+((lane>>4)<<2);
#pragma unroll
        for(int q=0;q<4;q++){
            float v=acc[i][q]; if(relu) v=fmaxf(v,0.f);
            short hi=f2bf(v);
            *(short*)(sm+bhi+so16(rb+q,col,pitch)) = hi;
            *(short*)(sm+blo+so16(rb+q,col,pitch)) = f2bf(v - bf2f(hi));
        }
    }
}
template<int NTL,int TPW>
__device__ __forceinline__ void st_tr(char* sm,int boff,int pitch,int lane,int w,
                                      const fx4* acc,bool relu){
#pragma unroll
    for(int i=0;i<TPW;i++){
        int t=w*TPW+i, mt=t>>NTL, nt=t&((1<<NTL)-1);
        int rn=(nt<<4)+(lane&15), cb=(mt<<4)+((lane>>4)<<2);
        bfx4 p;
#pragma unroll
        for(int q=0;q<4;q++){ float v=acc[i][q]; if(relu) v=fmaxf(v,0.f); p[q]=f2bf(v); }
        *(bfx4*)(sm+boff+so16(rn,cb,pitch)) = p;
    }
}
template<int NTL,int TPW>
__device__ __forceinline__ void st_tr_hilo(char* sm,int bhi,int blo,int pitch,int lane,int w,
                                           const fx4* acc,bool relu){
#pragma unroll
    for(int i=0;i<TPW;i++){
        int t=w*TPW+i, mt=t>>NTL, nt=t&((1<<NTL)-1);
        int rn=(nt<<4)+(lane&15), cb=(mt<<4)+((lane>>4)<<2);
        bfx4 ph, pl;
#pragma unroll
        for(int q=0;q<4;q++){
            float v=acc[i][q]; if(relu) v=fmaxf(v,0.f);
            short hi=f2bf(v); ph[q]=hi; pl[q]=f2bf(v - bf2f(hi));
        }
        *(bfx4*)(sm+bhi+so16(rn,cb,pitch)) = ph;
        *(bfx4*)(sm+blo+so16(rn,cb,pitch)) = pl;
    }
}
template<int TPW>
__device__ __forceinline__ void st_mp(char* sm,int lane,int w,const fx4* acc){
#pragma unroll
    for(int i=0;i<TPW;i++){
        int t=w*TPW+i, mt=t>>4, nt=t&15;
        int col=(nt<<4)+(lane&15), rb=(mt<<4)+((lane>>4)<<2);
#pragma unroll
        for(int q=0;q<4;q++) *(float*)(sm+mpoff(rb+q,col)) = acc[i][q];
    }
}

// ---- weight prepack: seg 0:Wp1hi 1:Wp1lo 2:We1hi 3:We2hi 4:We21hi (all 256x256) ----
// B-frag tile (kt,nt): out[((nt*8+kt)*64+lane)*8 + j] = W[kt*32+8*(lane/16)+j][nt*16+lane%16]
__global__ __launch_bounds__(256) void prepack_k(const float* __restrict__ Wp1,const float* __restrict__ We1,
                                                 const float* __restrict__ We2,const float* __restrict__ We21,
                                                 short* __restrict__ outp){
    int g = blockIdx.x; int seg = g>>5;
    int t = ((g&31)<<8) + threadIdx.x;          // [0,8192)
    int lane = t&63, tile = t>>6, kt = tile&7, nt = tile>>3;
    const float* W = (seg<2)? Wp1 : (seg==2)? We1 : (seg==3)? We2 : We21;
    int kb  = (kt<<5) + ((lane>>4)<<3);
    int col = (nt<<4) + (lane&15);
    bfx8 o;
#pragma unroll
    for(int j=0;j<8;j++){
        float v = W[(kb+j)*256 + col];
        short hi = f2bf(v);
        o[j] = (seg==1)? f2bf(v - bf2f(hi)) : hi;
    }
    ((bfx8*)outp)[seg*8192 + t] = o;
}

// ---- per-graph megakernel: 64 blocks x 512 threads (8 waves = 2/SIMD) ----
__global__ __launch_bounds__(512, 2) void mega_k(const float* __restrict__ x, const int* __restrict__ ei,
        const float* __restrict__ Wp2,  const float* __restrict__ We22,
        const float* __restrict__ l1W,  const float* __restrict__ l1b,
        const float* __restrict__ l2W,  const float* __restrict__ l2b,
        const short* __restrict__ pks,  float* __restrict__ out){
    extern __shared__ char sm[];
    const int tid = threadIdx.x, lane = tid&63, w = tid>>6, b = blockIdx.x;
    const bfx8* pkWp1hi = (const bfx8*)pks;
    const bfx8* pkWp1lo = pkWp1hi + 8192;
    const bfx8* pkWe1   = pkWp1hi + 16384;
    const bfx8* pkWe2   = pkWp1hi + 24576;
    const bfx8* pkWe21  = pkWp1hi + 32768;
    fx4 acc[8];

    // S0: zero A', stage X^T (bf16, swizzled); float4 global reads
    *(ix4*)(sm + OA + tid*16) = ix4{0,0,0,0};
#pragma unroll
    for(int ch=0; ch<8; ch++){
        int i2 = tid + (ch<<9);                   // [0,4096) float4 groups
        int r = i2>>6, c0 = (i2&63)<<2;
        fx4 v = *(const fx4*)(x + (size_t)(((b<<6)+r)<<8) + c0);
#pragma unroll
        for(int j=0;j<4;j++)
            *(short*)(sm + OB0 + so16(c0+j, r, 64)) = f2bf(v[j]);
    }
    __syncthreads();
    // S1: edges of graph b are e = b + 64*t  (structural: base=(e%64)*64)
#pragma unroll
    for(int q=0;q<2;q++){
        int e = b + (((tid<<1)+q)<<6);
        int s = ei[e]&63, d = ei[e+65536]&63;
        *(short*)(sm + OA + so16(s, d, 64)) = (short)0x3F80;   // 1.0bf16
    }
    __syncthreads();
    if(tid<64){                                                // A' = A + I (0/1 -> 1/2 exact)
        int off = OA + so16(tid, tid, 64);
        *(short*)(sm+off) = f2bf(bf2f(*(short*)(sm+off)) + 1.0f);
    }
    __syncthreads();

    // S2: M = A'X  -> Mhi(B1) + Mlo(B2), row-major pitch 256
    gemm_ll_t<4,2,8,false>(sm, OA,64, OB0,64, lane,w, acc);
    st_norm_hilo<4,8>(sm, OB1, OB2, 256, lane,w, acc, false);
    __syncthreads();

    // S3: He = relu(Mhi@We1) -> He^T (B3, pitch 64)
    gemm_lg_t<4,8,8,false>(sm, OB1,256, pkWe1, lane,w, acc);
    st_tr<4,8>(sm, OB3, 64, lane,w, acc, true);
    __builtin_amdgcn_sched_barrier(0);
    // S4: Hp = relu(M@Wp1) split-precision (3 passes)
    gemm_lg_t<4,8,8,false>(sm, OB1,256, pkWp1hi, lane,w, acc);
    __builtin_amdgcn_sched_barrier(0);
    gemm_lg_t<4,8,8,true >(sm, OB1,256, pkWp1lo, lane,w, acc);
    __builtin_amdgcn_sched_barrier(0);
    gemm_lg_t<4,8,8,true >(sm, OB2,256, pkWp1hi, lane,w, acc);
    __syncthreads();
    st_tr_hilo<4,8>(sm, OB0, OB2, 64, lane,w, acc, true);      // Hphi^T(B0), Hplo^T(B2)
    __syncthreads();

    // S5: Mp = A'(Hphi+Hplo), f32 in LDS (B0|B2)
    gemm_ll_t<4,2,8,false>(sm, OA,64, OB0,64, lane,w, acc);
    gemm_ll_t<4,2,8,true >(sm, OA,64, OB2,64, lane,w, acc);
    __syncthreads();
    st_mp<8>(sm, lane,w, acc);
    __syncthreads();

    // S6: Sp = Mp @ Wp2 (f32 VALU), 64x32
    {
        int r = tid>>3, sg = tid&7;
        float a0=0.f,a1=0.f,a2=0.f,a3=0.f;
#pragma unroll 4
        for(int c=0;c<256;c++){
            float m = *(const float*)(sm + mpoff(r,c));
            fx4 wv = *(const fx4*)(Wp2 + (c<<5) + (sg<<2));
            a0 += m*wv[0]; a1 += m*wv[1]; a2 += m*wv[2]; a3 += m*wv[3];
        }
        *(float*)(sm+OSP+so32(r,(sg<<2)+0,32))=a0;
        *(float*)(sm+OSP+so32(r,(sg<<2)+1,32))=a1;
        *(float*)(sm+OSP+so32(r,(sg<<2)+2,32))=a2;
        *(float*)(sm+OSP+so32(r,(sg<<2)+3,32))=a3;
    }
    __syncthreads();
    // S7: row-softmax (f32) -> S^T bf16 (OST)
    {
        int r = tid>>3, j = tid&7;
        float v0=*(const float*)(sm+OSP+so32(r,(j<<2)+0,32));
        float v1=*(const float*)(sm+OSP+so32(r,(j<<2)+1,32));
        float v2=*(const float*)(sm+OSP+so32(r,(j<<2)+2,32));
        float v3=*(const float*)(sm+OSP+so32(r,(j<<2)+3,32));
        float mx = fmaxf(fmaxf(v0,v1),fmaxf(v2,v3));
#pragma unroll
        for(int o=1;o<8;o<<=1) mx = fmaxf(mx, __shfl_xor(mx,o,64));
        float e0=__expf(v0-mx), e1=__expf(v1-mx), e2=__expf(v2-mx), e3=__expf(v3-mx);
        float s = e0+e1+e2+e3;
#pragma unroll
        for(int o=1;o<8;o<<=1) s += __shfl_xor(s,o,64);
        float inv = 1.f/s;
        *(short*)(sm+OST+so16((j<<2)+0,r,64)) = f2bf(e0*inv);
        *(short*)(sm+OST+so16((j<<2)+1,r,64)) = f2bf(e1*inv);
        *(short*)(sm+OST+so16((j<<2)+2,r,64)) = f2bf(e2*inv);
        *(short*)(sm+OST+so16((j<<2)+3,r,64)) = f2bf(e3*inv);
    }
    __syncthreads();

    // S8: Me = A'He -> row-major (B1)
    gemm_ll_t<4,2,8,false>(sm, OA,64, OB3,64, lane,w, acc);
    st_norm<4,8>(sm, OB1, 256, lane,w, acc, false);
    __syncthreads();
    // S9: Z = Me@We2 -> Z^T (B2)
    gemm_lg_t<4,8,8,false>(sm, OB1,256, pkWe2, lane,w, acc);
    st_tr<4,8>(sm, OB2, 64, lane,w, acc, false);
    __syncthreads();
    // S10: X2 = S^T Z (32x256) -> X2^T (OX2, pitch 32)
    gemm_ll_t<4,2,4,false>(sm, OST,64, OB2,64, lane,w, acc);
    st_tr<4,4>(sm, OX2, 32, lane,w, acc, false);
    __syncthreads();
    // S11: AS = A@S = A'S - S -> AS^T (OAS)
    {
        gemm_ll_t<1,2,1,false>(sm, OA,64, OST,64, lane,w, acc);
        int mt = w>>1, nt = w&1;
        int tcol = (nt<<4)+(lane&15), cb = (mt<<4)+((lane>>4)<<2);
        bfx4 p;
#pragma unroll
        for(int q=0;q<4;q++){
            float v = acc[0][q] - bf2f(*(const short*)(sm+OST+so16(tcol,cb+q,64)));
            p[q]=f2bf(v);
        }
        *(bfx4*)(sm+OAS+so16(tcol,cb,64)) = p;
    }
    __syncthreads();
    // S12: A2' = S^T AS + I -> OA2 (32x32)
    if(w<4){
        gemm_ll_t<1,2,1,false>(sm, OST,64, OAS,64, lane,w, acc);
        int mt=w>>1, nt=w&1;
        int col=(nt<<4)+(lane&15), rb=(mt<<4)+((lane>>4)<<2);
#pragma unroll
        for(int q=0;q<4;q++){
            float v = acc[0][q] + ((rb+q)==col ? 1.f : 0.f);
            *(short*)(sm+OA2+so16(rb+q,col,32)) = f2bf(v);
        }
    }
    __syncthreads();
    // S13: v = colsum(A2')
    if(tid<32){
        float s=0.f;
#pragma unroll
        for(int r=0;r<32;r++) s += bf2f(*(const short*)(sm+OA2+so16(r,tid,32)));
        *(float*)(sm+OV+(tid<<2)) = s;
    }
    __syncthreads();
    // S14: M2 = A2' X2 -> row-major (B3)
    gemm_ll_t<4,1,4,false>(sm, OA2,32, OX2,32, lane,w, acc);
    st_norm<4,4>(sm, OB3, 256, lane,w, acc, false);
    __syncthreads();
    // S15: He2 = relu(M2@We21) -> row-major (B0)
    gemm_lg_t<4,8,4,false>(sm, OB3,256, pkWe21, lane,w, acc);
    st_norm<4,4>(sm, OB0, 256, lane,w, acc, true);
    __syncthreads();
    // S16: w = v^T He2
    if(tid<256){
        float a=0.f;
#pragma unroll
        for(int n=0;n<32;n++)
            a += *(const float*)(sm+OV+(n<<2)) * bf2f(*(const short*)(sm+OB0+so16(n,tid,256)));
        *(float*)(sm+OW+(tid<<2)) = a;
    }
    __syncthreads();
    // S17: u = 0.125 * w @ We22 (f32 global weights)
    if(tid<256){
        float a=0.f;
#pragma unroll 8
        for(int k=0;k<256;k++) a += *(const float*)(sm+OW+(k<<2)) * We22[(k<<8)+tid];
        *(float*)(sm+OU+(tid<<2)) = 0.125f*a;
    }
    __syncthreads();
    // S18: t1 = relu(u@lin1 + b1)
    {
        float a = l1b[tid];
#pragma unroll 8
        for(int k=0;k<256;k++) a += *(const float*)(sm+OU+(k<<2)) * l1W[(k<<9)+tid];
        *(float*)(sm+OT1+(tid<<2)) = fmaxf(a,0.f);
    }
    __syncthreads();
    // S19: out = t1@lin2 + b2
    if(tid<256){
        float a = l2b[tid];
#pragma unroll 8
        for(int k=0;k<512;k++) a += *(const float*)(sm+OT1+(k<<2)) * l2W[(k<<8)+tid];
        out[(b<<8)+tid] = a;
    }
}

extern "C" void kernel_launch(void* const* d_in, const int* in_sizes, int n_in,
                              void* d_out, int out_size, void* d_ws, size_t ws_size,
                              hipStream_t stream) {
    const float* x    = (const float*)d_in[0];
    const int*   ei   = (const int*)d_in[1];
    const float* p0W1 = (const float*)d_in[3];
    const float* p0W2 = (const float*)d_in[4];
    const float* e0W1 = (const float*)d_in[5];
    const float* e0W2 = (const float*)d_in[6];
    // d_in[7], d_in[8]: pool1 weights are mathematically dead (softmax rows sum to 1 under mean-pool)
    const float* e1W1 = (const float*)d_in[9];
    const float* e1W2 = (const float*)d_in[10];
    const float* l1W  = (const float*)d_in[11];
    const float* l1b  = (const float*)d_in[12];
    const float* l2W  = (const float*)d_in[13];
    const float* l2b  = (const float*)d_in[14];
    float* out = (float*)d_out;
    short* pks = (short*)d_ws;          // 655360 B of packed bf16 weights

    hipFuncSetAttribute((const void*)mega_k, hipFuncAttributeMaxDynamicSharedMemorySize, LDS_TOTAL);
    prepack_k<<<160, 256, 0, stream>>>(p0W1, e0W1, e0W2, e1W1, pks);
    mega_k<<<64, 512, LDS_TOTAL, stream>>>(x, ei, p0W2, e1W2, l1W, l1b, l2W, l2b, pks, out);
}